// Round 3
// baseline (3296.766 us; speedup 1.0000x reference)
//
#include <hip/hip_runtime.h>

// ---------------------------------------------------------------------------
// GlobalMetaAggregator  R=2,K=3,N=16384,V=256,E=1,L=8,VE=128,LK=1,OUT=64,
// IN=256,HID=512,C=5.
// Round 3: two prior NaN rounds -> eliminate both environmental unknowns:
//  (a) respect ws_size: per-chunk full pipeline, host picks chunk size Nc
//      so footprint (3.4MB fixed + 13312 B/node * Nc) <= ws_size.
//  (b) runtime input-dtype detection (bf16 vs f32) via exponent-window vote
//      on raw_feats; all input loads + output stores branch on the flag.
// Correctness-first: vector-ALU GEMM, f32 accumulation, bf16 intermediates.
// ---------------------------------------------------------------------------

typedef unsigned short bf16_t;

__device__ __forceinline__ float bf2f(bf16_t u) {
    return __uint_as_float(((unsigned int)u) << 16);
}
__device__ __forceinline__ bf16_t f2bf(float f) {
    unsigned int u = __float_as_uint(f);
    u += 0x7FFFu + ((u >> 16) & 1u);   // RNE
    return (bf16_t)(u >> 16);
}
// dt: 0 = f32, 1 = bf16 (resolved; 2 = "use detected flag" at kernel entry)
__device__ __forceinline__ float ld1(const void* p, long i, int dt) {
    return dt ? bf2f(((const bf16_t*)p)[i]) : ((const float*)p)[i];
}
__device__ __forceinline__ float4 ld4(const void* p, long i, int dt) {
    if (dt) {
        ushort4 v = *(const ushort4*)((const bf16_t*)p + i);
        return make_float4(bf2f(v.x), bf2f(v.y), bf2f(v.z), bf2f(v.w));
    }
    return *(const float4*)((const float*)p + i);
}
__device__ __forceinline__ void st4(void* p, long i, int dt, float4 v) {
    if (dt) {
        ushort4 s; s.x = f2bf(v.x); s.y = f2bf(v.y); s.z = f2bf(v.z); s.w = f2bf(v.w);
        *(ushort4*)((bf16_t*)p + i) = s;
    } else {
        *(float4*)((float*)p + i) = v;
    }
}
// PReLU alpha = 0.25 exactly: f32 encoding has zero low-16 mantissa bits,
// bf16 encoding (0x3E80) is nonzero -> bit-exact discrimination.
__device__ __forceinline__ float decode_scalar(const void* p, int isbf) {
    if (!isbf) return *(const float*)p;
    unsigned int u = *(const unsigned int*)p;
    if ((u & 0xFFFFu) == 0u) return __uint_as_float(u);
    return bf2f((bf16_t)(u & 0xFFFFu));
}
__device__ __forceinline__ float wave_reduce(float v) {
#pragma unroll
    for (int o = 32; o > 0; o >>= 1) v += __shfl_down(v, o, 64);
    return v;
}

// ---------------------------------------------------------------------------
// dtype detector: sample 64 words of raw_feats (N(0,1)). If data is bf16,
// low u16 viewed as bf16 has exponent in [110,134] w.p. ~1; if f32, those
// bits are mantissa noise (~10% in window). Majority vote -> flag.
// ---------------------------------------------------------------------------
__global__ void detect_k(const unsigned int* __restrict__ w, long nwords,
                         int* __restrict__ flag)
{
    const int lane = threadIdx.x;            // 64 threads
    long idx = (long)lane * 997 + 13;
    if (idx >= nwords) idx = lane % (nwords > 0 ? nwords : 1);
    unsigned int word = w[idx];
    int e = (word >> 7) & 0xFF;
    int vote = (e >= 110 && e <= 134) ? 1 : 0;
    unsigned long long m = __ballot(vote);
    if (lane == 0) *flag = (__popcll(m) >= 32) ? 1 : 0;
}

// ---------------------------------------------------------------------------
// Generic tiled GEMM: C[z] = A[z] @ B[z] (+bias)(+PReLU), f32 accumulate.
// 64x64 tile, BK=16, 256 threads, 4x4 per thread. M,N,K multiples of tile.
// ---------------------------------------------------------------------------
#define BM 64
#define BN 64
#define BK 16

__global__ __launch_bounds__(256) void gemm64(
    const void* __restrict__ A, int adt, long aoff, long sAz, int lda,
    const void* __restrict__ B, int bdt, long boff, long sBz, int ldb,
    void* __restrict__ C, int cdt, long coff, long sCz, int ldc,
    const void* __restrict__ bias, long biasoff, long sBiasZ, int mode,
    const void* __restrict__ alpha_ptr, int K, const int* __restrict__ flag)
{
    const int isbf = *flag;
    if (adt == 2) adt = isbf;
    if (bdt == 2) bdt = isbf;
    if (cdt == 2) cdt = isbf;

    __shared__ __align__(16) float As[BK][BM + 4];
    __shared__ __align__(16) float Bs[BK][BN + 4];

    const int z  = blockIdx.z;
    const int t  = threadIdx.x;
    const int tx = t & 15, ty = t >> 4;
    const int am = t >> 2, ak = (t & 3) << 2;
    const int bn = tx << 2;

    const long aBase = aoff + z * sAz + (long)(blockIdx.y * BM + am) * lda + ak;
    const long bBase = boff + z * sBz + (long)ty * ldb + blockIdx.x * BN + bn;

    float acc[4][4] = {};
    for (int k0 = 0; k0 < K; k0 += BK) {
        float4 av = ld4(A, aBase + k0, adt);
        float4 bv = ld4(B, bBase + (long)k0 * ldb, bdt);
        __syncthreads();
        As[ak + 0][am] = av.x;
        As[ak + 1][am] = av.y;
        As[ak + 2][am] = av.z;
        As[ak + 3][am] = av.w;
        *(float4*)&Bs[ty][bn] = bv;
        __syncthreads();
#pragma unroll
        for (int k = 0; k < BK; k++) {
            float4 a4 = *(const float4*)&As[k][ty << 2];
            float4 b4 = *(const float4*)&Bs[k][tx << 2];
            float ar[4] = {a4.x, a4.y, a4.z, a4.w};
            float br[4] = {b4.x, b4.y, b4.z, b4.w};
#pragma unroll
            for (int i = 0; i < 4; i++)
#pragma unroll
                for (int j = 0; j < 4; j++) acc[i][j] += ar[i] * br[j];
        }
    }

    const int cm = blockIdx.y * BM + (ty << 2);
    const int cn = blockIdx.x * BN + (tx << 2);
    float bz[4] = {0.f, 0.f, 0.f, 0.f};
    if (mode >= 1) {
        long bb = biasoff + z * sBiasZ + cn;
        bz[0] = ld1(bias, bb + 0, isbf);
        bz[1] = ld1(bias, bb + 1, isbf);
        bz[2] = ld1(bias, bb + 2, isbf);
        bz[3] = ld1(bias, bb + 3, isbf);
    }
    const float alpha = (mode == 2) ? decode_scalar(alpha_ptr, isbf) : 0.f;
#pragma unroll
    for (int i = 0; i < 4; i++) {
        float o[4];
#pragma unroll
        for (int j = 0; j < 4; j++) {
            float v = acc[i][j] + bz[j];
            if (mode == 2) v = (v >= 0.f) ? v : alpha * v;
            o[j] = v;
        }
        st4(C, coff + z * sCz + (long)(cm + i) * ldc + cn, cdt,
            make_float4(o[0], o[1], o[2], o[3]));
    }
}

// ---------------------------------------------------------------------------
// Fused extra channel: me[l,:] = extra[n,l,:] @ eemb  (8x128 @ 128x256),
// then sigmoid-softmax pool over l -> EO[n,256] f32. One block per node.
// ---------------------------------------------------------------------------
__global__ __launch_bounds__(256) void extra_pool_k(
    const void* __restrict__ EX, long exoff,
    const void* __restrict__ EB, long eboff,
    const void* __restrict__ wx,
    float* __restrict__ EO, const int* __restrict__ flag)
{
    const int isbf = *flag;
    const int n = blockIdx.x, t = threadIdx.x;
    __shared__ float ex[1024];       // [8][128]
    float4 u = ld4(EX, exoff + (long)n * 1024 + t * 4, isbf);
    ex[t * 4 + 0] = u.x; ex[t * 4 + 1] = u.y;
    ex[t * 4 + 2] = u.z; ex[t * 4 + 3] = u.w;
    __syncthreads();

    float acc[8] = {};
#pragma unroll 4
    for (int v = 0; v < 128; v++) {
        float eb = ld1(EB, eboff + (long)v * 256 + t, isbf);
#pragma unroll
        for (int l = 0; l < 8; l++) acc[l] += ex[l * 128 + v] * eb;
    }

    const float w = ld1(wx, t, isbf);
    __shared__ float red[8][4];
    const int lane = t & 63, wid = t >> 6;
#pragma unroll
    for (int l = 0; l < 8; l++) {
        float pr = wave_reduce(acc[l] * w);
        if (lane == 0) red[l][wid] = pr;
    }
    __syncthreads();
    float gv[8], ssum = 0.f;
#pragma unroll
    for (int l = 0; l < 8; l++) {
        float sc = red[l][0] + red[l][1] + red[l][2] + red[l][3];
        float sg = 1.f / (1.f + expf(-sc));
        float e = expf(sg);
        gv[l] = e; ssum += e;
    }
    const float inv = 1.f / ssum;
    float o = 0.f;
#pragma unroll
    for (int l = 0; l < 8; l++) o += gv[l] * inv * acc[l];
    EO[(long)n * 256 + t] = o;
}

// ---------------------------------------------------------------------------
// LN over (C=5,HID=512)=2560 + PReLU, in place on bf16 [Nc,2560]
// ---------------------------------------------------------------------------
__global__ __launch_bounds__(256) void ln1_k(
    bf16_t* __restrict__ X, const void* __restrict__ g,
    const void* __restrict__ be, const void* __restrict__ alpha_ptr,
    const int* __restrict__ flag)
{
    const int isbf = *flag;
    const int n = blockIdx.x, t = threadIdx.x;
    bf16_t* row = X + (long)n * 2560;
    float v[10], s = 0.f, sq = 0.f;
#pragma unroll
    for (int i = 0; i < 10; i++) {
        float x = bf2f(row[i * 256 + t]);
        v[i] = x; s += x; sq += x * x;
    }
    __shared__ float redS[4], redQ[4];
    const int lane = t & 63, wid = t >> 6;
    float ws_ = wave_reduce(s), wq = wave_reduce(sq);
    if (lane == 0) { redS[wid] = ws_; redQ[wid] = wq; }
    __syncthreads();
    const float S = redS[0] + redS[1] + redS[2] + redS[3];
    const float Q = redQ[0] + redQ[1] + redQ[2] + redQ[3];
    const float mean = S * (1.f / 2560.f);
    const float rstd = rsqrtf(fmaxf(Q * (1.f / 2560.f) - mean * mean, 0.f) + 1e-5f);
    const float alpha = decode_scalar(alpha_ptr, isbf);
#pragma unroll
    for (int i = 0; i < 10; i++) {
        int e = i * 256 + t;
        float y = (v[i] - mean) * rstd * ld1(g, e, isbf) + ld1(be, e, isbf);
        row[e] = f2bf((y >= 0.f) ? y : alpha * y);
    }
}

// ---------------------------------------------------------------------------
// LN2 + PReLU + channel pool (C=5) -> H[n*1024 + rslot*512 + :512] (bf16)
// ---------------------------------------------------------------------------
__global__ __launch_bounds__(256) void ln2_pool_k(
    const bf16_t* __restrict__ X, const void* __restrict__ g,
    const void* __restrict__ be, const void* __restrict__ alpha_ptr,
    const void* __restrict__ wr, long wroff,
    bf16_t* __restrict__ H, int rslot, const int* __restrict__ flag)
{
    const int isbf = *flag;
    const int n = blockIdx.x, t = threadIdx.x;
    const bf16_t* row = X + (long)n * 2560;
    float v[5][2], s = 0.f, sq = 0.f;
#pragma unroll
    for (int c = 0; c < 5; c++)
#pragma unroll
        for (int hi = 0; hi < 2; hi++) {
            float x = bf2f(row[c * 512 + hi * 256 + t]);
            v[c][hi] = x; s += x; sq += x * x;
        }
    __shared__ float redS[4], redQ[4];
    const int lane = t & 63, wid = t >> 6;
    float ws_ = wave_reduce(s), wq = wave_reduce(sq);
    if (lane == 0) { redS[wid] = ws_; redQ[wid] = wq; }
    __syncthreads();
    const float S = redS[0] + redS[1] + redS[2] + redS[3];
    const float Q = redQ[0] + redQ[1] + redQ[2] + redQ[3];
    const float mean = S * (1.f / 2560.f);
    const float rstd = rsqrtf(fmaxf(Q * (1.f / 2560.f) - mean * mean, 0.f) + 1e-5f);
    const float alpha = decode_scalar(alpha_ptr, isbf);
    const float w0 = ld1(wr, wroff + t, isbf);
    const float w1 = ld1(wr, wroff + t + 256, isbf);
    float p[5];
#pragma unroll
    for (int c = 0; c < 5; c++) {
        p[c] = 0.f;
#pragma unroll
        for (int hi = 0; hi < 2; hi++) {
            int e = c * 512 + hi * 256 + t;
            float y = (v[c][hi] - mean) * rstd * ld1(g, e, isbf) + ld1(be, e, isbf);
            y = (y >= 0.f) ? y : alpha * y;
            v[c][hi] = y;
            p[c] += y * (hi ? w1 : w0);
        }
    }
    __shared__ float redP[5][4];
#pragma unroll
    for (int c = 0; c < 5; c++) {
        float pr = wave_reduce(p[c]);
        if (lane == 0) redP[c][wid] = pr;
    }
    __syncthreads();
    float gv[5], ssum = 0.f;
#pragma unroll
    for (int c = 0; c < 5; c++) {
        float sc = redP[c][0] + redP[c][1] + redP[c][2] + redP[c][3];
        float sg = 1.f / (1.f + expf(-sc));
        float e = expf(sg);
        gv[c] = e; ssum += e;
    }
    const float inv = 1.f / ssum;
#pragma unroll
    for (int hi = 0; hi < 2; hi++) {
        float o = 0.f;
#pragma unroll
        for (int c = 0; c < 5; c++) o += gv[c] * inv * v[c][hi];
        H[(long)n * 1024 + rslot * 512 + hi * 256 + t] = f2bf(o);
    }
}

// ---------------------------------------------------------------------------
// global attention pool over R=2: H[Nc,2,512] -> F[Nc,512] (both bf16)
// ---------------------------------------------------------------------------
__global__ __launch_bounds__(256) void gpool_k(
    const bf16_t* __restrict__ H, const void* __restrict__ wg,
    bf16_t* __restrict__ F, const int* __restrict__ flag)
{
    const int isbf = *flag;
    const int n = blockIdx.x, t = threadIdx.x;
    const bf16_t* base = H + (long)n * 1024;
    const float w0 = ld1(wg, t, isbf), w1 = ld1(wg, t + 256, isbf);
    float v[2][2], p[2];
#pragma unroll
    for (int r = 0; r < 2; r++) {
        v[r][0] = bf2f(base[r * 512 + t]);
        v[r][1] = bf2f(base[r * 512 + 256 + t]);
        p[r] = v[r][0] * w0 + v[r][1] * w1;
    }
    __shared__ float red[2][4];
    const int lane = t & 63, wid = t >> 6;
#pragma unroll
    for (int r = 0; r < 2; r++) {
        float pr = wave_reduce(p[r]);
        if (lane == 0) red[r][wid] = pr;
    }
    __syncthreads();
    float gv[2], ssum = 0.f;
#pragma unroll
    for (int r = 0; r < 2; r++) {
        float sc = red[r][0] + red[r][1] + red[r][2] + red[r][3];
        float sg = 1.f / (1.f + expf(-sc));
        float e = expf(sg);
        gv[r] = e; ssum += e;
    }
    const float inv = 1.f / ssum;
#pragma unroll
    for (int hi = 0; hi < 2; hi++) {
        F[(long)n * 512 + hi * 256 + t] =
            f2bf((gv[0] * v[0][hi] + gv[1] * v[1][hi]) * inv);
    }
}

// ---------------------------------------------------------------------------
extern "C" void kernel_launch(void* const* d_in, const int* in_sizes, int n_in,
                              void* d_out, int out_size, void* d_ws, size_t ws_size,
                              hipStream_t stream)
{
    const void* raw   = d_in[0];   // (2,3,16384,256)
    const void* extra = d_in[1];   // (2,1,16384,8,128)
    const void* lbl   = d_in[2];   // (2,1,16384,64)
    const void* femb  = d_in[3];   // (2,3,256,256)
    const void* eemb  = d_in[4];   // (2,1,128,256)
    const void* lemb  = d_in[5];   // (2,1,64,256)
    const void* wx    = d_in[6];   // (1,256)
    const void* wr    = d_in[7];   // (2,512)
    const void* wg    = d_in[8];   // (512,)
    const void* W1    = d_in[9];   // (5,256,512)
    const void* b1    = d_in[10];  // (5,512)
    const void* g1    = d_in[11];
    const void* be1   = d_in[12];
    const void* a1    = d_in[13];
    const void* W2    = d_in[14];  // (5,512,512)
    const void* b2    = d_in[15];
    const void* g2    = d_in[16];
    const void* be2   = d_in[17];
    const void* a2    = d_in[18];
    const void* Wf1   = d_in[19];  // (512,512)
    const void* bf1   = d_in[20];
    const void* af    = d_in[21];
    const void* Wf2   = d_in[22];  // (512,64)
    const void* bf2b  = d_in[23];

    // ---- workspace plan: flag(256B) + Mf/Ml f32 (3.4MB) + chunk arena ----
    int*   flag = (int*)d_ws;
    char*  p0   = (char*)d_ws + 256;
    float* Mf   = (float*)p0;                 // [2][3][256][512] f32
    float* Ml   = Mf + 786432;                // [2][64][512] f32
    char*  arena = (char*)(Ml + 65536);
    const size_t fixedBytes = 256 + (786432 + 65536) * sizeof(float);

    int Nc = 4096;
    while (Nc > 64 && fixedBytes + (size_t)Nc * 13312 > ws_size) Nc >>= 1;
    const int NCH = 16384 / Nc;

    bf16_t* x1c  = (bf16_t*)arena;                            // [Nc,2560] bf16
    bf16_t* x2c  = (bf16_t*)(arena + (size_t)Nc * 5120);      // [Nc,2560] bf16
    float*  eoc  = (float*) (arena + (size_t)Nc * 10240);     // [Nc,256]  f32
    bf16_t* hbc  = (bf16_t*)(arena + (size_t)Nc * 11264);     // [Nc,2,512] bf16
    bf16_t* finc = x1c;                                       // [Nc,512] alias
    bf16_t* zbc  = (bf16_t*)((char*)x1c + (size_t)Nc * 1024); // [Nc,512] alias

    dim3 blk(256);

    // ---- dtype detection (every call; same work per call) ----
    detect_k<<<1, 64, 0, stream>>>((const unsigned int*)raw,
                                   (long)in_sizes[0] / 2, flag);

    // ---- fold embeddings into W1 ----
    // Mf[r,k] = femb[r,k] (256x256) @ W1[k] (256x512)
    for (int r = 0; r < 2; r++) {
        gemm64<<<dim3(8, 4, 3), blk, 0, stream>>>(
            femb, 2, (long)r * 196608, 65536, 256,
            W1,   2, 0, 131072, 512,
            Mf,   0, (long)r * 393216, 131072, 512,
            nullptr, 0, 0, 0, nullptr, 256, flag);
    }
    // Ml[r] = lemb[r] (64x256) @ W1[4] (256x512)
    gemm64<<<dim3(8, 1, 2), blk, 0, stream>>>(
        lemb, 2, 0, 16384, 256,
        W1,   2, 4L * 131072, 0, 512,
        Ml,   0, 0, 32768, 512,
        nullptr, 0, 0, 0, nullptr, 256, flag);

    for (int c = 0; c < NCH; c++) {
        const long n0 = (long)c * Nc;
        for (int r = 0; r < 2; r++) {
            // fused extra GEMM + pool -> eoc f32
            extra_pool_k<<<Nc, blk, 0, stream>>>(
                extra, (long)r * 16777216 + n0 * 1024,
                eemb,  (long)r * 32768, wx, eoc, flag);

            // x1 ch0..2 = raw[r,k,chunk] @ Mf[r,k] + b1[k]
            gemm64<<<dim3(8, Nc / 64, 3), blk, 0, stream>>>(
                raw, 2, (long)r * 12582912 + n0 * 256, 4194304, 256,
                Mf,  0, (long)r * 393216, 131072, 512,
                x1c, 1, 0, 512, 2560,
                b1, 0, 512, 1, nullptr, 256, flag);
            // x1 ch3 = eoc @ W1[3] + b1[3]
            gemm64<<<dim3(8, Nc / 64, 1), blk, 0, stream>>>(
                eoc, 0, 0, 0, 256,
                W1,  2, 3L * 131072, 0, 512,
                x1c, 1, 3L * 512, 0, 2560,
                b1, 3L * 512, 0, 1, nullptr, 256, flag);
            // x1 ch4 = lbl[r,chunk] (Nc x 64) @ Ml[r] + b1[4]
            gemm64<<<dim3(8, Nc / 64, 1), blk, 0, stream>>>(
                lbl, 2, (long)r * 1048576 + n0 * 64, 0, 64,
                Ml,  0, (long)r * 32768, 0, 512,
                x1c, 1, 4L * 512, 0, 2560,
                b1, 4L * 512, 0, 1, nullptr, 64, flag);

            ln1_k<<<Nc, blk, 0, stream>>>(x1c, g1, be1, a1, flag);

            // x2[:,ch,:] = x1[:,ch,:] @ W2[ch] + b2[ch]
            gemm64<<<dim3(8, Nc / 64, 5), blk, 0, stream>>>(
                x1c, 1, 0, 512, 2560,
                W2,  2, 0, 262144, 512,
                x2c, 1, 0, 512, 2560,
                b2, 0, 512, 1, nullptr, 512, flag);

            ln2_pool_k<<<Nc, blk, 0, stream>>>(x2c, g2, be2, a2,
                                               wr, (long)r * 512, hbc, r, flag);
        }

        gpool_k<<<Nc, blk, 0, stream>>>(hbc, wg, finc, flag);

        // z = PReLU(fin @ Wf1 + bf1, af)
        gemm64<<<dim3(8, Nc / 64, 1), blk, 0, stream>>>(
            finc, 1, 0, 0, 512,
            Wf1,  2, 0, 0, 512,
            zbc,  1, 0, 0, 512,
            bf1, 0, 0, 2, af, 512, flag);
        // out[chunk] = z @ Wf2 + bf2  (output dtype per flag)
        gemm64<<<dim3(1, Nc / 64, 1), blk, 0, stream>>>(
            zbc,   1, 0, 0, 512,
            Wf2,   2, 0, 0, 64,
            d_out, 2, n0 * 64, 0, 64,
            bf2b, 0, 0, 1, nullptr, 512, flag);
    }
}

// Round 4
// 1464.911 us; speedup vs baseline: 2.2505x; 2.2505x over previous
//
#include <hip/hip_runtime.h>

// ---------------------------------------------------------------------------
// GlobalMetaAggregator  R=2,K=3,N=16384,V=256,E=1,L=8,VE=128,LK=1,OUT=64,
// IN=256,HID=512,C=5.
// Round 4: GEMMs moved from vector-ALU (71 TF ceiling, VALUBusy 65%) to
// bf16 MFMA 16x16x32. Weights pre-transposed to [N][K] bf16 so both MFMA
// operands stage with contiguous 16B loads. Extra-channel GEMM batched
// ([Nc*8,128]@[128,256] MFMA) + separate pool. dtype-detect kept.
// ---------------------------------------------------------------------------

typedef unsigned short bf16_t;
using ushort8v = __attribute__((ext_vector_type(8))) unsigned short;
using bf16x8   = __attribute__((ext_vector_type(8))) __bf16;
using f32x4    = __attribute__((ext_vector_type(4))) float;

__device__ __forceinline__ float bf2f(bf16_t u) {
    return __uint_as_float(((unsigned int)u) << 16);
}
__device__ __forceinline__ bf16_t f2bf(float f) {
    unsigned int u = __float_as_uint(f);
    u += 0x7FFFu + ((u >> 16) & 1u);   // RNE
    return (bf16_t)(u >> 16);
}
__device__ __forceinline__ float ld1(const void* p, long i, int dt) {
    return dt ? bf2f(((const bf16_t*)p)[i]) : ((const float*)p)[i];
}
__device__ __forceinline__ float4 ld4(const void* p, long i, int dt) {
    if (dt) {
        ushort4 v = *(const ushort4*)((const bf16_t*)p + i);
        return make_float4(bf2f(v.x), bf2f(v.y), bf2f(v.z), bf2f(v.w));
    }
    return *(const float4*)((const float*)p + i);
}
// load 8 elements as bf16 bits (converting if f32 source)
__device__ __forceinline__ ushort8v ld8bf(const void* p, long i, int dt) {
    if (dt) return *(const ushort8v*)((const bf16_t*)p + i);
    const float* f = (const float*)p + i;
    float4 a = *(const float4*)f, b = *(const float4*)(f + 4);
    ushort8v r;
    r[0] = f2bf(a.x); r[1] = f2bf(a.y); r[2] = f2bf(a.z); r[3] = f2bf(a.w);
    r[4] = f2bf(b.x); r[5] = f2bf(b.y); r[6] = f2bf(b.z); r[7] = f2bf(b.w);
    return r;
}
// PReLU alpha=0.25: f32 encoding has zero low-16 bits, bf16 nonzero.
__device__ __forceinline__ float decode_scalar(const void* p, int isbf) {
    if (!isbf) return *(const float*)p;
    unsigned int u = *(const unsigned int*)p;
    if ((u & 0xFFFFu) == 0u) return __uint_as_float(u);
    return bf2f((bf16_t)(u & 0xFFFFu));
}
__device__ __forceinline__ float wave_reduce(float v) {
#pragma unroll
    for (int o = 32; o > 0; o >>= 1) v += __shfl_down(v, o, 64);
    return v;
}

// ---------------------------------------------------------------------------
// dtype detector (bf16 vs f32), majority vote on exponent window.
// ---------------------------------------------------------------------------
__global__ void detect_k(const unsigned int* __restrict__ w, long nwords,
                         int* __restrict__ flag)
{
    const int lane = threadIdx.x;            // 64 threads
    long idx = (long)lane * 997 + 13;
    if (idx >= nwords) idx = lane % (nwords > 0 ? nwords : 1);
    unsigned int word = w[idx];
    int e = (word >> 7) & 0xFF;
    int vote = (e >= 110 && e <= 134) ? 1 : 0;
    unsigned long long m = __ballot(vote);
    if (lane == 0) *flag = (__popcll(m) >= 32) ? 1 : 0;
}

// ---------------------------------------------------------------------------
// transpose: in [K][N] (flag dtype) -> out [N][K] bf16, batched over z
// ---------------------------------------------------------------------------
__global__ __launch_bounds__(256) void transT_k(
    const void* __restrict__ in, long inoff, long sInZ, int Kd, int Nd,
    bf16_t* __restrict__ out, long outoff, long sOutZ,
    const int* __restrict__ flag)
{
    const int isbf = *flag;
    const long z = blockIdx.z;
    long idx = (long)blockIdx.x * 256 + threadIdx.x;
    if (idx >= (long)Kd * Nd) return;
    int k = (int)(idx / Nd), n = (int)(idx % Nd);
    out[outoff + z * sOutZ + (long)n * Kd + k] =
        f2bf(ld1(in, inoff + z * sInZ + idx, isbf));
}

// ---------------------------------------------------------------------------
// fold GEMM (small): C^T = (A@B)^T stored bf16.  A [M][K], B [K][N] flag
// dtype; out CT [N][M] bf16 (ldcT = M-stride).  64x64 tile vector ALU.
// ---------------------------------------------------------------------------
__global__ __launch_bounds__(256) void fold_gemmT_k(
    const void* __restrict__ A, long aoff, long sAz, int lda,
    const void* __restrict__ B, long boff, long sBz, int ldb,
    bf16_t* __restrict__ CT, long coff, long sCz, int ldcT,
    int K, const int* __restrict__ flag)
{
    const int isbf = *flag;
    __shared__ __align__(16) float As[16][68];
    __shared__ __align__(16) float Bs[16][68];
    const int z = blockIdx.z, t = threadIdx.x;
    const int tx = t & 15, ty = t >> 4;
    const int am = t >> 2, ak = (t & 3) << 2;
    const int bn = tx << 2;
    const long aBase = aoff + z * sAz + (long)(blockIdx.y * 64 + am) * lda + ak;
    const long bBase = boff + z * sBz + (long)ty * ldb + blockIdx.x * 64 + bn;
    float acc[4][4] = {};
    for (int k0 = 0; k0 < K; k0 += 16) {
        float4 av = ld4(A, aBase + k0, isbf);
        float4 bv = ld4(B, bBase + (long)k0 * ldb, isbf);
        __syncthreads();
        As[ak + 0][am] = av.x; As[ak + 1][am] = av.y;
        As[ak + 2][am] = av.z; As[ak + 3][am] = av.w;
        *(float4*)&Bs[ty][bn] = bv;
        __syncthreads();
#pragma unroll
        for (int k = 0; k < 16; k++) {
            float4 a4 = *(const float4*)&As[k][ty << 2];
            float4 b4 = *(const float4*)&Bs[k][tx << 2];
            float ar[4] = {a4.x, a4.y, a4.z, a4.w};
            float br[4] = {b4.x, b4.y, b4.z, b4.w};
#pragma unroll
            for (int i = 0; i < 4; i++)
#pragma unroll
                for (int j = 0; j < 4; j++) acc[i][j] += ar[i] * br[j];
        }
    }
    const int cm = blockIdx.y * 64 + (ty << 2);
    const int cn = blockIdx.x * 64 + (tx << 2);
#pragma unroll
    for (int i = 0; i < 4; i++)
#pragma unroll
        for (int j = 0; j < 4; j++)
            CT[coff + z * sCz + (long)(cn + j) * ldcT + (cm + i)] = f2bf(acc[i][j]);
}

// ---------------------------------------------------------------------------
// MFMA GEMM: C[z] = A[z] @ BT[z]^T (+bias)(+PReLU).
// A [M][K] (adt: 0=f32,1=bf16,2=flag), BT [N][K] bf16, f32 accum.
// Tile 128 x BN_, BK=32, 4 waves (2x2), wave tile 64 x WNW_.
// MODE: 0 none, 1 +bias, 2 +bias+PReLU.  CD: 1 bf16 out, 2 flag-dtype out.
// M % 128 == 0, N % BN_ == 0, K % 32 == 0.
// ---------------------------------------------------------------------------
template <int BN_, int WNW_, int MODE, int CD>
__global__ __launch_bounds__(256) void mgemm(
    const void* __restrict__ A, int adt, long aoff, long sAz, int lda,
    const bf16_t* __restrict__ BT, long boff, long sBz,
    void* __restrict__ C, long coff, long sCz, int ldc,
    const void* __restrict__ bias, long biasoff, long sBiasZ,
    const void* __restrict__ alpha_ptr, int K,
    const int* __restrict__ flag)
{
    constexpr int NJ = WNW_ / 16;
    const int isbf = *flag;
    const int adt_ = (adt == 2) ? isbf : adt;
    const int cdt = (CD == 2) ? isbf : 1;

    __shared__ __align__(16) unsigned short As[128 * 40];
    __shared__ __align__(16) unsigned short Bs[BN_ * 40];

    const int t = threadIdx.x;
    const int lane = t & 63, w = t >> 6;
    const int quad = lane >> 4, r16 = lane & 15;
    const int wy = w >> 1, wx = w & 1;
    const long z = blockIdx.z;
    const long blockM = (long)blockIdx.y * 128;
    const int  blockN = blockIdx.x * BN_;

    f32x4 acc[4][NJ];
    const f32x4 zero4 = {0.f, 0.f, 0.f, 0.f};
#pragma unroll
    for (int i = 0; i < 4; i++)
#pragma unroll
        for (int j = 0; j < NJ; j++) acc[i][j] = zero4;

    const long aBase = aoff + z * sAz;
    const long bBase = boff + z * sBz;

    for (int k0 = 0; k0 < K; k0 += 32) {
        ushort8v av[2], bv[BN_ / 64];
#pragma unroll
        for (int c = 0; c < 2; c++) {
            int lin = t + c * 256;
            int m = lin >> 2, kq = (lin & 3) * 8;
            av[c] = ld8bf(A, aBase + (blockM + m) * (long)lda + k0 + kq, adt_);
        }
#pragma unroll
        for (int c = 0; c < BN_ / 64; c++) {
            int lin = t + c * 256;
            int n = lin >> 2, kq = (lin & 3) * 8;
            bv[c] = *(const ushort8v*)(BT + bBase + (long)(blockN + n) * K + k0 + kq);
        }
        __syncthreads();
#pragma unroll
        for (int c = 0; c < 2; c++) {
            int lin = t + c * 256;
            int m = lin >> 2, kq = (lin & 3) * 8;
            *(ushort8v*)&As[m * 40 + kq] = av[c];
        }
#pragma unroll
        for (int c = 0; c < BN_ / 64; c++) {
            int lin = t + c * 256;
            int n = lin >> 2, kq = (lin & 3) * 8;
            *(ushort8v*)&Bs[n * 40 + kq] = bv[c];
        }
        __syncthreads();

        bf16x8 af[4], bfr[NJ];
#pragma unroll
        for (int i = 0; i < 4; i++) {
            int m = wy * 64 + i * 16 + r16;
            af[i] = __builtin_bit_cast(bf16x8, *(const ushort8v*)&As[m * 40 + quad * 8]);
        }
#pragma unroll
        for (int j = 0; j < NJ; j++) {
            int n = wx * WNW_ + j * 16 + r16;
            bfr[j] = __builtin_bit_cast(bf16x8, *(const ushort8v*)&Bs[n * 40 + quad * 8]);
        }
#pragma unroll
        for (int i = 0; i < 4; i++)
#pragma unroll
            for (int j = 0; j < NJ; j++)
                acc[i][j] = __builtin_amdgcn_mfma_f32_16x16x32_bf16(
                    af[i], bfr[j], acc[i][j], 0, 0, 0);
    }

    const float alpha = (MODE == 2) ? decode_scalar(alpha_ptr, isbf) : 0.f;
#pragma unroll
    for (int j = 0; j < NJ; j++) {
        const int n = blockN + wx * WNW_ + j * 16 + r16;
        const float bz = (MODE >= 1) ? ld1(bias, biasoff + z * sBiasZ + n, isbf) : 0.f;
#pragma unroll
        for (int i = 0; i < 4; i++) {
            const long m0 = blockM + wy * 64 + i * 16 + quad * 4;
#pragma unroll
            for (int rg = 0; rg < 4; rg++) {
                float v = acc[i][j][rg] + bz;
                if (MODE == 2) v = (v >= 0.f) ? v : alpha * v;
                const long off = coff + z * sCz + (m0 + rg) * (long)ldc + n;
                if (cdt) ((bf16_t*)C)[off] = f2bf(v);
                else     ((float*)C)[off] = v;
            }
        }
    }
}

// ---------------------------------------------------------------------------
// extra pool: reads me bf16 [Nc*8,256]; sigmoid-softmax over L=8 -> EO f32
// ---------------------------------------------------------------------------
__global__ __launch_bounds__(256) void pool_extra_k(
    const bf16_t* __restrict__ ME, const void* __restrict__ wx,
    float* __restrict__ EO, const int* __restrict__ flag)
{
    const int isbf = *flag;
    const int n = blockIdx.x, t = threadIdx.x;
    const bf16_t* base = ME + (long)n * 2048;
    float v[8];
#pragma unroll
    for (int l = 0; l < 8; l++) v[l] = bf2f(base[l * 256 + t]);
    const float w = ld1(wx, t, isbf);
    __shared__ float red[8][4];
    const int lane = t & 63, wid = t >> 6;
#pragma unroll
    for (int l = 0; l < 8; l++) {
        float pr = wave_reduce(v[l] * w);
        if (lane == 0) red[l][wid] = pr;
    }
    __syncthreads();
    float gv[8], ssum = 0.f;
#pragma unroll
    for (int l = 0; l < 8; l++) {
        float sc = red[l][0] + red[l][1] + red[l][2] + red[l][3];
        float sg = 1.f / (1.f + expf(-sc));
        float e = expf(sg);
        gv[l] = e; ssum += e;
    }
    const float inv = 1.f / ssum;
    float o = 0.f;
#pragma unroll
    for (int l = 0; l < 8; l++) o += gv[l] * inv * v[l];
    EO[(long)n * 256 + t] = o;
}

// ---------------------------------------------------------------------------
// LN over (5,512)=2560 + PReLU, in place, bf16 [Nc,2560]
// ---------------------------------------------------------------------------
__global__ __launch_bounds__(256) void ln1_k(
    bf16_t* __restrict__ X, const void* __restrict__ g,
    const void* __restrict__ be, const void* __restrict__ alpha_ptr,
    const int* __restrict__ flag)
{
    const int isbf = *flag;
    const int n = blockIdx.x, t = threadIdx.x;
    bf16_t* row = X + (long)n * 2560;
    float v[10], s = 0.f, sq = 0.f;
#pragma unroll
    for (int i = 0; i < 10; i++) {
        float x = bf2f(row[i * 256 + t]);
        v[i] = x; s += x; sq += x * x;
    }
    __shared__ float redS[4], redQ[4];
    const int lane = t & 63, wid = t >> 6;
    float ws_ = wave_reduce(s), wq = wave_reduce(sq);
    if (lane == 0) { redS[wid] = ws_; redQ[wid] = wq; }
    __syncthreads();
    const float S = redS[0] + redS[1] + redS[2] + redS[3];
    const float Q = redQ[0] + redQ[1] + redQ[2] + redQ[3];
    const float mean = S * (1.f / 2560.f);
    const float rstd = rsqrtf(fmaxf(Q * (1.f / 2560.f) - mean * mean, 0.f) + 1e-5f);
    const float alpha = decode_scalar(alpha_ptr, isbf);
#pragma unroll
    for (int i = 0; i < 10; i++) {
        int e = i * 256 + t;
        float y = (v[i] - mean) * rstd * ld1(g, e, isbf) + ld1(be, e, isbf);
        row[e] = f2bf((y >= 0.f) ? y : alpha * y);
    }
}

// ---------------------------------------------------------------------------
// LN2 + PReLU + channel pool (C=5) -> H[n*1024 + rslot*512 + :] bf16
// ---------------------------------------------------------------------------
__global__ __launch_bounds__(256) void ln2_pool_k(
    const bf16_t* __restrict__ X, const void* __restrict__ g,
    const void* __restrict__ be, const void* __restrict__ alpha_ptr,
    const void* __restrict__ wr, long wroff,
    bf16_t* __restrict__ H, int rslot, const int* __restrict__ flag)
{
    const int isbf = *flag;
    const int n = blockIdx.x, t = threadIdx.x;
    const bf16_t* row = X + (long)n * 2560;
    float v[5][2], s = 0.f, sq = 0.f;
#pragma unroll
    for (int c = 0; c < 5; c++)
#pragma unroll
        for (int hi = 0; hi < 2; hi++) {
            float x = bf2f(row[c * 512 + hi * 256 + t]);
            v[c][hi] = x; s += x; sq += x * x;
        }
    __shared__ float redS[4], redQ[4];
    const int lane = t & 63, wid = t >> 6;
    float ws_ = wave_reduce(s), wq = wave_reduce(sq);
    if (lane == 0) { redS[wid] = ws_; redQ[wid] = wq; }
    __syncthreads();
    const float S = redS[0] + redS[1] + redS[2] + redS[3];
    const float Q = redQ[0] + redQ[1] + redQ[2] + redQ[3];
    const float mean = S * (1.f / 2560.f);
    const float rstd = rsqrtf(fmaxf(Q * (1.f / 2560.f) - mean * mean, 0.f) + 1e-5f);
    const float alpha = decode_scalar(alpha_ptr, isbf);
    const float w0 = ld1(wr, wroff + t, isbf);
    const float w1 = ld1(wr, wroff + t + 256, isbf);
    float p[5];
#pragma unroll
    for (int c = 0; c < 5; c++) {
        p[c] = 0.f;
#pragma unroll
        for (int hi = 0; hi < 2; hi++) {
            int e = c * 512 + hi * 256 + t;
            float y = (v[c][hi] - mean) * rstd * ld1(g, e, isbf) + ld1(be, e, isbf);
            y = (y >= 0.f) ? y : alpha * y;
            v[c][hi] = y;
            p[c] += y * (hi ? w1 : w0);
        }
    }
    __shared__ float redP[5][4];
#pragma unroll
    for (int c = 0; c < 5; c++) {
        float pr = wave_reduce(p[c]);
        if (lane == 0) redP[c][wid] = pr;
    }
    __syncthreads();
    float gv[5], ssum = 0.f;
#pragma unroll
    for (int c = 0; c < 5; c++) {
        float sc = redP[c][0] + redP[c][1] + redP[c][2] + redP[c][3];
        float sg = 1.f / (1.f + expf(-sc));
        float e = expf(sg);
        gv[c] = e; ssum += e;
    }
    const float inv = 1.f / ssum;
#pragma unroll
    for (int hi = 0; hi < 2; hi++) {
        float o = 0.f;
#pragma unroll
        for (int c = 0; c < 5; c++) o += gv[c] * inv * v[c][hi];
        H[(long)n * 1024 + rslot * 512 + hi * 256 + t] = f2bf(o);
    }
}

// ---------------------------------------------------------------------------
// global pool over R=2: H[Nc,2,512] -> F[Nc,512] bf16
// ---------------------------------------------------------------------------
__global__ __launch_bounds__(256) void gpool_k(
    const bf16_t* __restrict__ H, const void* __restrict__ wg,
    bf16_t* __restrict__ F, const int* __restrict__ flag)
{
    const int isbf = *flag;
    const int n = blockIdx.x, t = threadIdx.x;
    const bf16_t* base = H + (long)n * 1024;
    const float w0 = ld1(wg, t, isbf), w1 = ld1(wg, t + 256, isbf);
    float v[2][2], p[2];
#pragma unroll
    for (int r = 0; r < 2; r++) {
        v[r][0] = bf2f(base[r * 512 + t]);
        v[r][1] = bf2f(base[r * 512 + 256 + t]);
        p[r] = v[r][0] * w0 + v[r][1] * w1;
    }
    __shared__ float red[2][4];
    const int lane = t & 63, wid = t >> 6;
#pragma unroll
    for (int r = 0; r < 2; r++) {
        float pr = wave_reduce(p[r]);
        if (lane == 0) red[r][wid] = pr;
    }
    __syncthreads();
    float gv[2], ssum = 0.f;
#pragma unroll
    for (int r = 0; r < 2; r++) {
        float sc = red[r][0] + red[r][1] + red[r][2] + red[r][3];
        float sg = 1.f / (1.f + expf(-sc));
        float e = expf(sg);
        gv[r] = e; ssum += e;
    }
    const float inv = 1.f / ssum;
#pragma unroll
    for (int hi = 0; hi < 2; hi++) {
        F[(long)n * 512 + hi * 256 + t] =
            f2bf((gv[0] * v[0][hi] + gv[1] * v[1][hi]) * inv);
    }
}

// ---------------------------------------------------------------------------
extern "C" void kernel_launch(void* const* d_in, const int* in_sizes, int n_in,
                              void* d_out, int out_size, void* d_ws, size_t ws_size,
                              hipStream_t stream)
{
    const void* raw   = d_in[0];   // (2,3,16384,256)
    const void* extra = d_in[1];   // (2,1,16384,8,128)
    const void* lbl   = d_in[2];   // (2,1,16384,64)
    const void* femb  = d_in[3];   // (2,3,256,256)
    const void* eemb  = d_in[4];   // (2,1,128,256)
    const void* lemb  = d_in[5];   // (2,1,64,256)
    const void* wx    = d_in[6];   // (1,256)
    const void* wr    = d_in[7];   // (2,512)
    const void* wg    = d_in[8];   // (512,)
    const void* W1    = d_in[9];   // (5,256,512)
    const void* b1    = d_in[10];  // (5,512)
    const void* g1    = d_in[11];
    const void* be1   = d_in[12];
    const void* a1    = d_in[13];
    const void* W2    = d_in[14];  // (5,512,512)
    const void* b2    = d_in[15];
    const void* g2    = d_in[16];
    const void* be2   = d_in[17];
    const void* a2    = d_in[18];
    const void* Wf1   = d_in[19];  // (512,512)
    const void* bf1   = d_in[20];
    const void* af    = d_in[21];
    const void* Wf2   = d_in[22];  // (512,64)
    const void* bf2b  = d_in[23];

    // ---- workspace: flag | transposed bf16 weights | chunk arena ----
    int*    flag  = (int*)d_ws;
    bf16_t* MfT   = (bf16_t*)((char*)d_ws + 256);  // [2][3][512][256]
    bf16_t* MlT   = MfT + 786432;                  // [2][512][64]
    bf16_t* W1c3T = MlT + 65536;                   // [512][256]
    bf16_t* W2T   = W1c3T + 131072;                // [5][512][512]
    bf16_t* Wf1T  = W2T + 1310720;                 // [512][512]
    bf16_t* Wf2T  = Wf1T + 262144;                 // [64][512]
    bf16_t* eT    = Wf2T + 32768;                  // [2][256][128]
    char*   arena = (char*)(eT + 65536);
    const size_t fixedBytes = 256 + 2654208 * 2;

    int Nc = 4096;
    while (Nc > 128 && fixedBytes + (size_t)Nc * 13312 > ws_size) Nc >>= 1;
    const int NCH = 16384 / Nc;

    bf16_t* x1c = (bf16_t*)arena;                          // [Nc,2560]
    bf16_t* x2c = (bf16_t*)(arena + (size_t)Nc * 5120);    // [Nc,2560]
    float*  eoc = (float*) (arena + (size_t)Nc * 10240);   // [Nc,256] f32
    bf16_t* hbc = (bf16_t*)(arena + (size_t)Nc * 11264);   // [Nc,2,512]
    bf16_t* mec = x2c;                                     // [Nc*8,256] alias (4096B/node < 5120B)
    bf16_t* finc = x1c;                                    // [Nc,512] alias
    bf16_t* zbc = (bf16_t*)((char*)x1c + (size_t)Nc * 1024);

    dim3 blk(256);

    detect_k<<<1, 64, 0, stream>>>((const unsigned int*)raw,
                                   (long)in_sizes[0] / 2, flag);

    // ---- weight transposes (bf16 [N][K]) ----
    transT_k<<<dim3(1024, 1, 5), blk, 0, stream>>>(W2, 0, 262144, 512, 512,
                                                   W2T, 0, 262144, flag);
    transT_k<<<dim3(512, 1, 1), blk, 0, stream>>>(W1, 3L * 131072, 0, 256, 512,
                                                  W1c3T, 0, 0, flag);
    transT_k<<<dim3(1024, 1, 1), blk, 0, stream>>>(Wf1, 0, 0, 512, 512,
                                                   Wf1T, 0, 0, flag);
    transT_k<<<dim3(128, 1, 1), blk, 0, stream>>>(Wf2, 0, 0, 512, 64,
                                                  Wf2T, 0, 0, flag);
    transT_k<<<dim3(128, 1, 2), blk, 0, stream>>>(eemb, 0, 32768, 128, 256,
                                                  eT, 0, 32768, flag);

    // ---- folds: MfT[r,k] = (femb[r,k] @ W1[k])^T, MlT[r] = (lemb[r]@W1[4])^T
    for (int r = 0; r < 2; r++) {
        fold_gemmT_k<<<dim3(8, 4, 3), blk, 0, stream>>>(
            femb, (long)r * 196608, 65536, 256,
            W1, 0, 131072, 512,
            MfT, (long)r * 393216, 131072, 256, 256, flag);
    }
    fold_gemmT_k<<<dim3(8, 1, 2), blk, 0, stream>>>(
        lemb, 0, 16384, 256,
        W1, 4L * 131072, 0, 512,
        MlT, 0, 32768, 64, 256, flag);

    for (int c = 0; c < NCH; c++) {
        const long n0 = (long)c * Nc;
        for (int r = 0; r < 2; r++) {
            // me = extra[r,chunk] [Nc*8,128] @ eembT -> [Nc*8,256] bf16
            mgemm<128, 64, 0, 1><<<dim3(2, Nc * 8 / 128, 1), blk, 0, stream>>>(
                extra, 2, (long)r * 16777216 + n0 * 1024, 0, 128,
                eT, (long)r * 32768, 0,
                mec, 0, 0, 256,
                nullptr, 0, 0, nullptr, 128, flag);
            pool_extra_k<<<Nc, blk, 0, stream>>>(mec, wx, eoc, flag);

            // x1 ch0..2 = raw @ MfT^T + b1
            mgemm<128, 64, 1, 1><<<dim3(4, Nc / 128, 3), blk, 0, stream>>>(
                raw, 2, (long)r * 12582912 + n0 * 256, 4194304, 256,
                MfT, (long)r * 393216, 131072,
                x1c, 0, 512, 2560,
                b1, 0, 512, nullptr, 256, flag);
            // x1 ch3 = eoc(f32) @ W1c3T^T + b1[3]
            mgemm<128, 64, 1, 1><<<dim3(4, Nc / 128, 1), blk, 0, stream>>>(
                eoc, 0, 0, 0, 256,
                W1c3T, 0, 0,
                x1c, 3L * 512, 0, 2560,
                b1, 3L * 512, 0, nullptr, 256, flag);
            // x1 ch4 = lbl @ MlT^T + b1[4]
            mgemm<128, 64, 1, 1><<<dim3(4, Nc / 128, 1), blk, 0, stream>>>(
                lbl, 2, (long)r * 1048576 + n0 * 64, 0, 64,
                MlT, (long)r * 32768, 0,
                x1c, 4L * 512, 0, 2560,
                b1, 4L * 512, 0, nullptr, 64, flag);

            ln1_k<<<Nc, blk, 0, stream>>>(x1c, g1, be1, a1, flag);

            // x2[:,z,:] = x1[:,z,:] @ W2T[z]^T + b2[z]
            mgemm<128, 64, 1, 1><<<dim3(4, Nc / 128, 5), blk, 0, stream>>>(
                x1c, 1, 0, 512, 2560,
                W2T, 0, 262144,
                x2c, 0, 512, 2560,
                b2, 0, 512, nullptr, 512, flag);

            ln2_pool_k<<<Nc, blk, 0, stream>>>(x2c, g2, be2, a2,
                                               wr, (long)r * 512, hbc, r, flag);
        }

        gpool_k<<<Nc, blk, 0, stream>>>(hbc, wg, finc, flag);

        // z = PReLU(fin @ Wf1T^T + bf1)
        mgemm<128, 64, 2, 1><<<dim3(4, Nc / 128, 1), blk, 0, stream>>>(
            finc, 1, 0, 0, 512,
            Wf1T, 0, 0,
            zbc, 0, 0, 512,
            bf1, 0, 0, af, 512, flag);
        // out = z @ Wf2T^T + bf2
        mgemm<64, 32, 1, 2><<<dim3(1, Nc / 128, 1), blk, 0, stream>>>(
            zbc, 1, 0, 0, 512,
            Wf2T, 0, 0,
            d_out, n0 * 64, 0, 64,
            bf2b, 0, 0, nullptr, 512, flag);
    }
}

// Round 5
// 1063.775 us; speedup vs baseline: 3.0991x; 1.3771x over previous
//
#include <hip/hip_runtime.h>

// ---------------------------------------------------------------------------
// GlobalMetaAggregator  R=2,K=3,N=16384,V=256,E=1,L=8,VE=128,LK=1,OUT=64,
// IN=256,HID=512,C=5.
// Round 5: ws_size is ~512MB (seen via harness 537MB fill) -> single chunk
// Nc=16384, relations/channels merged into GEMM z-dim via (z/zdiv,z%zdiv)
// stride pairs. ~20 large-grid dispatches instead of ~70 small ones.
// ---------------------------------------------------------------------------

typedef unsigned short bf16_t;
using ushort8v = __attribute__((ext_vector_type(8))) unsigned short;
using bf16x8   = __attribute__((ext_vector_type(8))) __bf16;
using f32x4    = __attribute__((ext_vector_type(4))) float;

__device__ __forceinline__ float bf2f(bf16_t u) {
    return __uint_as_float(((unsigned int)u) << 16);
}
__device__ __forceinline__ bf16_t f2bf(float f) {
    unsigned int u = __float_as_uint(f);
    u += 0x7FFFu + ((u >> 16) & 1u);   // RNE
    return (bf16_t)(u >> 16);
}
__device__ __forceinline__ float ld1(const void* p, long i, int dt) {
    return dt ? bf2f(((const bf16_t*)p)[i]) : ((const float*)p)[i];
}
__device__ __forceinline__ float4 ld4(const void* p, long i, int dt) {
    if (dt) {
        ushort4 v = *(const ushort4*)((const bf16_t*)p + i);
        return make_float4(bf2f(v.x), bf2f(v.y), bf2f(v.z), bf2f(v.w));
    }
    return *(const float4*)((const float*)p + i);
}
__device__ __forceinline__ ushort8v ld8bf(const void* p, long i, int dt) {
    if (dt) return *(const ushort8v*)((const bf16_t*)p + i);
    const float* f = (const float*)p + i;
    float4 a = *(const float4*)f, b = *(const float4*)(f + 4);
    ushort8v r;
    r[0] = f2bf(a.x); r[1] = f2bf(a.y); r[2] = f2bf(a.z); r[3] = f2bf(a.w);
    r[4] = f2bf(b.x); r[5] = f2bf(b.y); r[6] = f2bf(b.z); r[7] = f2bf(b.w);
    return r;
}
__device__ __forceinline__ float decode_scalar(const void* p, int isbf) {
    if (!isbf) return *(const float*)p;
    unsigned int u = *(const unsigned int*)p;
    if ((u & 0xFFFFu) == 0u) return __uint_as_float(u);
    return bf2f((bf16_t)(u & 0xFFFFu));
}
__device__ __forceinline__ float wave_reduce(float v) {
#pragma unroll
    for (int o = 32; o > 0; o >>= 1) v += __shfl_down(v, o, 64);
    return v;
}

// ---------------------------------------------------------------------------
__global__ void detect_k(const unsigned int* __restrict__ w, long nwords,
                         int* __restrict__ flag)
{
    const int lane = threadIdx.x;
    long idx = (long)lane * 997 + 13;
    if (idx >= nwords) idx = lane % (nwords > 0 ? nwords : 1);
    unsigned int word = w[idx];
    int e = (word >> 7) & 0xFF;
    int vote = (e >= 110 && e <= 134) ? 1 : 0;
    unsigned long long m = __ballot(vote);
    if (lane == 0) *flag = (__popcll(m) >= 32) ? 1 : 0;
}

// ---------------------------------------------------------------------------
// transpose: in [K][N] (flag dtype) -> out [N][K] bf16, batched over z
// ---------------------------------------------------------------------------
__global__ __launch_bounds__(256) void transT_k(
    const void* __restrict__ in, long inoff, long sInZ, int Kd, int Nd,
    bf16_t* __restrict__ out, long outoff, long sOutZ,
    const int* __restrict__ flag)
{
    const int isbf = *flag;
    const long z = blockIdx.z;
    long idx = (long)blockIdx.x * 256 + threadIdx.x;
    if (idx >= (long)Kd * Nd) return;
    int k = (int)(idx / Nd), n = (int)(idx % Nd);
    out[outoff + z * sOutZ + (long)n * Kd + k] =
        f2bf(ld1(in, inoff + z * sInZ + idx, isbf));
}

// ---------------------------------------------------------------------------
// fold GEMM (small): CT = (A@B)^T bf16.  A [M][K], B [K][N] flag dtype.
// ---------------------------------------------------------------------------
__global__ __launch_bounds__(256) void fold_gemmT_k(
    const void* __restrict__ A, long aoff, long sAz, int lda,
    const void* __restrict__ B, long boff, long sBz, int ldb,
    bf16_t* __restrict__ CT, long coff, long sCz, int ldcT,
    int K, const int* __restrict__ flag)
{
    const int isbf = *flag;
    __shared__ __align__(16) float As[16][68];
    __shared__ __align__(16) float Bs[16][68];
    const int z = blockIdx.z, t = threadIdx.x;
    const int tx = t & 15, ty = t >> 4;
    const int am = t >> 2, ak = (t & 3) << 2;
    const int bn = tx << 2;
    const long aBase = aoff + z * sAz + (long)(blockIdx.y * 64 + am) * lda + ak;
    const long bBase = boff + z * sBz + (long)ty * ldb + blockIdx.x * 64 + bn;
    float acc[4][4] = {};
    for (int k0 = 0; k0 < K; k0 += 16) {
        float4 av = ld4(A, aBase + k0, isbf);
        float4 bv = ld4(B, bBase + (long)k0 * ldb, isbf);
        __syncthreads();
        As[ak + 0][am] = av.x; As[ak + 1][am] = av.y;
        As[ak + 2][am] = av.z; As[ak + 3][am] = av.w;
        *(float4*)&Bs[ty][bn] = bv;
        __syncthreads();
#pragma unroll
        for (int k = 0; k < 16; k++) {
            float4 a4 = *(const float4*)&As[k][ty << 2];
            float4 b4 = *(const float4*)&Bs[k][tx << 2];
            float ar[4] = {a4.x, a4.y, a4.z, a4.w};
            float br[4] = {b4.x, b4.y, b4.z, b4.w};
#pragma unroll
            for (int i = 0; i < 4; i++)
#pragma unroll
                for (int j = 0; j < 4; j++) acc[i][j] += ar[i] * br[j];
        }
    }
    const int cm = blockIdx.y * 64 + (ty << 2);
    const int cn = blockIdx.x * 64 + (tx << 2);
#pragma unroll
    for (int i = 0; i < 4; i++)
#pragma unroll
        for (int j = 0; j < 4; j++)
            CT[coff + z * sCz + (long)(cn + j) * ldcT + (cm + i)] = f2bf(acc[i][j]);
}

// ---------------------------------------------------------------------------
// MFMA GEMM: C[z] = A[z] @ BT[z]^T (+bias)(+PReLU), f32 accumulate.
// Per-z offsets: with zq=z/zdiv, zr=z%zdiv, offset = off + zq*s1 + zr*s2.
// A [M][K] (adt 0=f32,1=bf16,2=flag), BT [N][K] bf16.
// Tile 128 x BN_, BK=32, 4 waves (2x2), wave tile 64 x WNW_.
// MODE: 0 none, 1 +bias, 2 +bias+PReLU.  CD: 1 bf16 out, 2 flag-dtype out.
// ---------------------------------------------------------------------------
template <int BN_, int WNW_, int MODE, int CD>
__global__ __launch_bounds__(256) void mgemm(
    const void* __restrict__ A, int adt, long aoff, long sA1, long sA2, int lda,
    const bf16_t* __restrict__ BT, long boff, long sB1, long sB2,
    void* __restrict__ C, long coff, long sC1, long sC2, int ldc,
    const void* __restrict__ bias, long biasoff, long sBi1, long sBi2,
    const void* __restrict__ alpha_ptr, int K, int zdiv,
    const int* __restrict__ flag)
{
    constexpr int NJ = WNW_ / 16;
    const int isbf = *flag;
    const int adt_ = (adt == 2) ? isbf : adt;
    const int cdt = (CD == 2) ? isbf : 1;

    __shared__ __align__(16) unsigned short As[128 * 40];
    __shared__ __align__(16) unsigned short Bs[BN_ * 40];

    const int t = threadIdx.x;
    const int lane = t & 63, w = t >> 6;
    const int quad = lane >> 4, r16 = lane & 15;
    const int wy = w >> 1, wx = w & 1;
    const int z = blockIdx.z;
    const int zq = z / zdiv, zr = z % zdiv;
    const long blockM = (long)blockIdx.y * 128;
    const int  blockN = blockIdx.x * BN_;

    f32x4 acc[4][NJ];
    const f32x4 zero4 = {0.f, 0.f, 0.f, 0.f};
#pragma unroll
    for (int i = 0; i < 4; i++)
#pragma unroll
        for (int j = 0; j < NJ; j++) acc[i][j] = zero4;

    const long aBase = aoff + zq * sA1 + zr * sA2;
    const long bBase = boff + zq * sB1 + zr * sB2;

    for (int k0 = 0; k0 < K; k0 += 32) {
        ushort8v av[2], bv[BN_ / 64];
#pragma unroll
        for (int c = 0; c < 2; c++) {
            int lin = t + c * 256;
            int m = lin >> 2, kq = (lin & 3) * 8;
            av[c] = ld8bf(A, aBase + (blockM + m) * (long)lda + k0 + kq, adt_);
        }
#pragma unroll
        for (int c = 0; c < BN_ / 64; c++) {
            int lin = t + c * 256;
            int n = lin >> 2, kq = (lin & 3) * 8;
            bv[c] = *(const ushort8v*)(BT + bBase + (long)(blockN + n) * K + k0 + kq);
        }
        __syncthreads();
#pragma unroll
        for (int c = 0; c < 2; c++) {
            int lin = t + c * 256;
            int m = lin >> 2, kq = (lin & 3) * 8;
            *(ushort8v*)&As[m * 40 + kq] = av[c];
        }
#pragma unroll
        for (int c = 0; c < BN_ / 64; c++) {
            int lin = t + c * 256;
            int n = lin >> 2, kq = (lin & 3) * 8;
            *(ushort8v*)&Bs[n * 40 + kq] = bv[c];
        }
        __syncthreads();

        bf16x8 af[4], bfr[NJ];
#pragma unroll
        for (int i = 0; i < 4; i++) {
            int m = wy * 64 + i * 16 + r16;
            af[i] = __builtin_bit_cast(bf16x8, *(const ushort8v*)&As[m * 40 + quad * 8]);
        }
#pragma unroll
        for (int j = 0; j < NJ; j++) {
            int n = wx * WNW_ + j * 16 + r16;
            bfr[j] = __builtin_bit_cast(bf16x8, *(const ushort8v*)&Bs[n * 40 + quad * 8]);
        }
#pragma unroll
        for (int i = 0; i < 4; i++)
#pragma unroll
            for (int j = 0; j < NJ; j++)
                acc[i][j] = __builtin_amdgcn_mfma_f32_16x16x32_bf16(
                    af[i], bfr[j], acc[i][j], 0, 0, 0);
    }

    const float alpha = (MODE == 2) ? decode_scalar(alpha_ptr, isbf) : 0.f;
    const long cBase = coff + zq * sC1 + zr * sC2;
#pragma unroll
    for (int j = 0; j < NJ; j++) {
        const int n = blockN + wx * WNW_ + j * 16 + r16;
        const float bz = (MODE >= 1)
            ? ld1(bias, biasoff + zq * sBi1 + zr * sBi2 + n, isbf) : 0.f;
#pragma unroll
        for (int i = 0; i < 4; i++) {
            const long m0 = blockM + wy * 64 + i * 16 + quad * 4;
#pragma unroll
            for (int rg = 0; rg < 4; rg++) {
                float v = acc[i][j][rg] + bz;
                if (MODE == 2) v = (v >= 0.f) ? v : alpha * v;
                const long off = cBase + (m0 + rg) * (long)ldc + n;
                if (cdt) ((bf16_t*)C)[off] = f2bf(v);
                else     ((float*)C)[off] = v;
            }
        }
    }
}

// ---------------------------------------------------------------------------
// extra pool: ME bf16 [2][Nc*8,256]; sigmoid-softmax over L=8 -> EO f32
// grid (Nc, 2)
// ---------------------------------------------------------------------------
__global__ __launch_bounds__(256) void pool_extra_k(
    const bf16_t* __restrict__ ME, long sMEz, const void* __restrict__ wx,
    float* __restrict__ EO, long sEOz, const int* __restrict__ flag)
{
    const int isbf = *flag;
    const int n = blockIdx.x, t = threadIdx.x;
    const bf16_t* base = ME + blockIdx.y * sMEz + (long)n * 2048;
    float v[8];
#pragma unroll
    for (int l = 0; l < 8; l++) v[l] = bf2f(base[l * 256 + t]);
    const float w = ld1(wx, t, isbf);
    __shared__ float red[8][4];
    const int lane = t & 63, wid = t >> 6;
#pragma unroll
    for (int l = 0; l < 8; l++) {
        float pr = wave_reduce(v[l] * w);
        if (lane == 0) red[l][wid] = pr;
    }
    __syncthreads();
    float gv[8], ssum = 0.f;
#pragma unroll
    for (int l = 0; l < 8; l++) {
        float sc = red[l][0] + red[l][1] + red[l][2] + red[l][3];
        float sg = 1.f / (1.f + expf(-sc));
        float e = expf(sg);
        gv[l] = e; ssum += e;
    }
    const float inv = 1.f / ssum;
    float o = 0.f;
#pragma unroll
    for (int l = 0; l < 8; l++) o += gv[l] * inv * v[l];
    EO[blockIdx.y * sEOz + (long)n * 256 + t] = o;
}

// ---------------------------------------------------------------------------
// LN over (5,512)=2560 + PReLU, in place, bf16; grid = #rows
// ---------------------------------------------------------------------------
__global__ __launch_bounds__(256) void ln1_k(
    bf16_t* __restrict__ X, const void* __restrict__ g,
    const void* __restrict__ be, const void* __restrict__ alpha_ptr,
    const int* __restrict__ flag)
{
    const int isbf = *flag;
    const int n = blockIdx.x, t = threadIdx.x;
    bf16_t* row = X + (long)n * 2560;
    float v[10], s = 0.f, sq = 0.f;
#pragma unroll
    for (int i = 0; i < 10; i++) {
        float x = bf2f(row[i * 256 + t]);
        v[i] = x; s += x; sq += x * x;
    }
    __shared__ float redS[4], redQ[4];
    const int lane = t & 63, wid = t >> 6;
    float ws_ = wave_reduce(s), wq = wave_reduce(sq);
    if (lane == 0) { redS[wid] = ws_; redQ[wid] = wq; }
    __syncthreads();
    const float S = redS[0] + redS[1] + redS[2] + redS[3];
    const float Q = redQ[0] + redQ[1] + redQ[2] + redQ[3];
    const float mean = S * (1.f / 2560.f);
    const float rstd = rsqrtf(fmaxf(Q * (1.f / 2560.f) - mean * mean, 0.f) + 1e-5f);
    const float alpha = decode_scalar(alpha_ptr, isbf);
#pragma unroll
    for (int i = 0; i < 10; i++) {
        int e = i * 256 + t;
        float y = (v[i] - mean) * rstd * ld1(g, e, isbf) + ld1(be, e, isbf);
        row[e] = f2bf((y >= 0.f) ? y : alpha * y);
    }
}

// ---------------------------------------------------------------------------
// LN2 + PReLU + channel pool (C=5) -> H[n*1024 + r*512 + :] bf16
// grid (Nc, 2): blockIdx.y = relation
// ---------------------------------------------------------------------------
__global__ __launch_bounds__(256) void ln2_pool_k(
    const bf16_t* __restrict__ X, long sXz, const void* __restrict__ g,
    const void* __restrict__ be, const void* __restrict__ alpha_ptr,
    const void* __restrict__ wr,
    bf16_t* __restrict__ H, const int* __restrict__ flag)
{
    const int isbf = *flag;
    const int n = blockIdx.x, t = threadIdx.x, rr = blockIdx.y;
    const bf16_t* row = X + rr * sXz + (long)n * 2560;
    float v[5][2], s = 0.f, sq = 0.f;
#pragma unroll
    for (int c = 0; c < 5; c++)
#pragma unroll
        for (int hi = 0; hi < 2; hi++) {
            float x = bf2f(row[c * 512 + hi * 256 + t]);
            v[c][hi] = x; s += x; sq += x * x;
        }
    __shared__ float redS[4], redQ[4];
    const int lane = t & 63, wid = t >> 6;
    float ws_ = wave_reduce(s), wq = wave_reduce(sq);
    if (lane == 0) { redS[wid] = ws_; redQ[wid] = wq; }
    __syncthreads();
    const float S = redS[0] + redS[1] + redS[2] + redS[3];
    const float Q = redQ[0] + redQ[1] + redQ[2] + redQ[3];
    const float mean = S * (1.f / 2560.f);
    const float rstd = rsqrtf(fmaxf(Q * (1.f / 2560.f) - mean * mean, 0.f) + 1e-5f);
    const float alpha = decode_scalar(alpha_ptr, isbf);
    const float w0 = ld1(wr, (long)rr * 512 + t, isbf);
    const float w1 = ld1(wr, (long)rr * 512 + t + 256, isbf);
    float p[5];
#pragma unroll
    for (int c = 0; c < 5; c++) {
        p[c] = 0.f;
#pragma unroll
        for (int hi = 0; hi < 2; hi++) {
            int e = c * 512 + hi * 256 + t;
            float y = (v[c][hi] - mean) * rstd * ld1(g, e, isbf) + ld1(be, e, isbf);
            y = (y >= 0.f) ? y : alpha * y;
            v[c][hi] = y;
            p[c] += y * (hi ? w1 : w0);
        }
    }
    __shared__ float redP[5][4];
#pragma unroll
    for (int c = 0; c < 5; c++) {
        float pr = wave_reduce(p[c]);
        if (lane == 0) redP[c][wid] = pr;
    }
    __syncthreads();
    float gv[5], ssum = 0.f;
#pragma unroll
    for (int c = 0; c < 5; c++) {
        float sc = redP[c][0] + redP[c][1] + redP[c][2] + redP[c][3];
        float sg = 1.f / (1.f + expf(-sc));
        float e = expf(sg);
        gv[c] = e; ssum += e;
    }
    const float inv = 1.f / ssum;
#pragma unroll
    for (int hi = 0; hi < 2; hi++) {
        float o = 0.f;
#pragma unroll
        for (int c = 0; c < 5; c++) o += gv[c] * inv * v[c][hi];
        H[(long)n * 1024 + rr * 512 + hi * 256 + t] = f2bf(o);
    }
}

// ---------------------------------------------------------------------------
// global pool over R=2: H[Nc,2,512] -> F[Nc,512] bf16
// ---------------------------------------------------------------------------
__global__ __launch_bounds__(256) void gpool_k(
    const bf16_t* __restrict__ H, const void* __restrict__ wg,
    bf16_t* __restrict__ F, const int* __restrict__ flag)
{
    const int isbf = *flag;
    const int n = blockIdx.x, t = threadIdx.x;
    const bf16_t* base = H + (long)n * 1024;
    const float w0 = ld1(wg, t, isbf), w1 = ld1(wg, t + 256, isbf);
    float v[2][2], p[2];
#pragma unroll
    for (int r = 0; r < 2; r++) {
        v[r][0] = bf2f(base[r * 512 + t]);
        v[r][1] = bf2f(base[r * 512 + 256 + t]);
        p[r] = v[r][0] * w0 + v[r][1] * w1;
    }
    __shared__ float red[2][4];
    const int lane = t & 63, wid = t >> 6;
#pragma unroll
    for (int r = 0; r < 2; r++) {
        float pr = wave_reduce(p[r]);
        if (lane == 0) red[r][wid] = pr;
    }
    __syncthreads();
    float gv[2], ssum = 0.f;
#pragma unroll
    for (int r = 0; r < 2; r++) {
        float sc = red[r][0] + red[r][1] + red[r][2] + red[r][3];
        float sg = 1.f / (1.f + expf(-sc));
        float e = expf(sg);
        gv[r] = e; ssum += e;
    }
    const float inv = 1.f / ssum;
#pragma unroll
    for (int hi = 0; hi < 2; hi++) {
        F[(long)n * 512 + hi * 256 + t] =
            f2bf((gv[0] * v[0][hi] + gv[1] * v[1][hi]) * inv);
    }
}

// ---------------------------------------------------------------------------
extern "C" void kernel_launch(void* const* d_in, const int* in_sizes, int n_in,
                              void* d_out, int out_size, void* d_ws, size_t ws_size,
                              hipStream_t stream)
{
    const void* raw   = d_in[0];   // (2,3,16384,256)
    const void* extra = d_in[1];   // (2,1,16384,8,128)
    const void* lbl   = d_in[2];   // (2,1,16384,64)
    const void* femb  = d_in[3];   // (2,3,256,256)
    const void* eemb  = d_in[4];   // (2,1,128,256)
    const void* lemb  = d_in[5];   // (2,1,64,256)
    const void* wx    = d_in[6];   // (1,256)
    const void* wr    = d_in[7];   // (2,512)
    const void* wg    = d_in[8];   // (512,)
    const void* W1    = d_in[9];   // (5,256,512)
    const void* b1    = d_in[10];  // (5,512)
    const void* g1    = d_in[11];
    const void* be1   = d_in[12];
    const void* a1    = d_in[13];
    const void* W2    = d_in[14];  // (5,512,512)
    const void* b2    = d_in[15];
    const void* g2    = d_in[16];
    const void* be2   = d_in[17];
    const void* a2    = d_in[18];
    const void* Wf1   = d_in[19];  // (512,512)
    const void* bf1   = d_in[20];
    const void* af    = d_in[21];
    const void* Wf2   = d_in[22];  // (512,64)
    const void* bf2b  = d_in[23];

    // ---- workspace: flag | transposed bf16 weights | arena ----
    int*    flag  = (int*)d_ws;
    bf16_t* MfT   = (bf16_t*)((char*)d_ws + 256);  // [2][3][512][256]
    bf16_t* MlT   = MfT + 786432;                  // [2][512][64]
    bf16_t* W1c3T = MlT + 65536;                   // [512][256]
    bf16_t* W2T   = W1c3T + 131072;                // [5][512][512]
    bf16_t* Wf1T  = W2T + 1310720;                 // [512][512]
    bf16_t* Wf2T  = Wf1T + 262144;                 // [64][512]
    bf16_t* eT    = Wf2T + 32768;                  // [2][256][128]
    char*   arena = (char*)(eT + 65536);
    const size_t fixedBytes = 256 + 2654208 * 2;

    // per-node arena bytes: x1 2*5120 + x2 2*5120 + eoc 2*1024 + hbc 2048
    int Nc = 16384;
    while (Nc > 128 && fixedBytes + (size_t)Nc * 24576 > ws_size) Nc >>= 1;
    const int NCH = 16384 / Nc;

    bf16_t* x1  = (bf16_t*)arena;                           // [2][Nc][2560]
    bf16_t* x2  = (bf16_t*)(arena + (size_t)Nc * 10240);    // [2][Nc][2560]
    float*  eo  = (float*) (arena + (size_t)Nc * 20480);    // [2][Nc][256] f32
    bf16_t* hbc = (bf16_t*)(arena + (size_t)Nc * 22528);    // [Nc][2][512]
    bf16_t* mec = x1;                                       // [2][Nc*8][256] alias (8192B/node <= 10240)
    bf16_t* fin = x2;                                       // [Nc][512] alias
    bf16_t* zb  = x2 + (size_t)Nc * 512;                    // [Nc][512] alias

    dim3 blk(256);

    detect_k<<<1, 64, 0, stream>>>((const unsigned int*)raw,
                                   (long)in_sizes[0] / 2, flag);

    // ---- weight transposes (bf16 [N][K]) ----
    transT_k<<<dim3(1024, 1, 5), blk, 0, stream>>>(W2, 0, 262144, 512, 512,
                                                   W2T, 0, 262144, flag);
    transT_k<<<dim3(512, 1, 1), blk, 0, stream>>>(W1, 3L * 131072, 0, 256, 512,
                                                  W1c3T, 0, 0, flag);
    transT_k<<<dim3(1024, 1, 1), blk, 0, stream>>>(Wf1, 0, 0, 512, 512,
                                                   Wf1T, 0, 0, flag);
    transT_k<<<dim3(128, 1, 1), blk, 0, stream>>>(Wf2, 0, 0, 512, 64,
                                                  Wf2T, 0, 0, flag);
    transT_k<<<dim3(128, 1, 2), blk, 0, stream>>>(eemb, 0, 32768, 128, 256,
                                                  eT, 0, 32768, flag);

    // ---- folds: MfT[r,k] = (femb[r,k]@W1[k])^T, MlT[r] = (lemb[r]@W1[4])^T
    for (int r = 0; r < 2; r++) {
        fold_gemmT_k<<<dim3(8, 4, 3), blk, 0, stream>>>(
            femb, (long)r * 196608, 65536, 256,
            W1, 0, 131072, 512,
            MfT, (long)r * 393216, 131072, 256, 256, flag);
    }
    fold_gemmT_k<<<dim3(8, 1, 2), blk, 0, stream>>>(
        lemb, 0, 16384, 256,
        W1, 4L * 131072, 0, 512,
        MlT, 0, 32768, 64, 256, flag);

    for (int c = 0; c < NCH; c++) {
        const long n0 = (long)c * Nc;

        // me[r] = extra[r,chunk] [Nc*8,128] @ eT[r]^T -> mec [2][Nc*8][256]
        mgemm<128, 64, 0, 1><<<dim3(2, Nc * 8 / 128, 2), blk, 0, stream>>>(
            extra, 2, n0 * 1024, 16777216, 0, 128,
            eT, 0, 32768, 0,
            mec, 0, (long)Nc * 8 * 256, 0, 256,
            nullptr, 0, 0, 0, nullptr, 128, 1, flag);
        // pool over L=8 -> eo[2][Nc][256]
        pool_extra_k<<<dim3(Nc, 2), blk, 0, stream>>>(
            mec, (long)Nc * 8 * 256, wx, eo, (long)Nc * 256, flag);

        // x1 ch0..2 (both relations): z=r*3+k, zdiv=3
        mgemm<128, 64, 1, 1><<<dim3(4, Nc / 128, 6), blk, 0, stream>>>(
            raw, 2, n0 * 256, 12582912, 4194304, 256,
            MfT, 0, 393216, 131072,
            x1, 0, (long)Nc * 2560, 512, 2560,
            b1, 0, 0, 512, nullptr, 256, 3, flag);
        // x1 ch3 = eo[r] @ W1c3T^T + b1[3]: z=r, zdiv=1
        mgemm<128, 64, 1, 1><<<dim3(4, Nc / 128, 2), blk, 0, stream>>>(
            eo, 0, 0, (long)Nc * 256, 0, 256,
            W1c3T, 0, 0, 0,
            x1, 3L * 512, (long)Nc * 2560, 0, 2560,
            b1, 3L * 512, 0, 0, nullptr, 256, 1, flag);
        // x1 ch4 = lbl[r,chunk] @ MlT[r]^T + b1[4]: z=r, zdiv=1
        mgemm<128, 64, 1, 1><<<dim3(4, Nc / 128, 2), blk, 0, stream>>>(
            lbl, 2, n0 * 64, 1048576, 0, 64,
            MlT, 0, 32768, 0,
            x1, 4L * 512, (long)Nc * 2560, 0, 2560,
            b1, 4L * 512, 0, 0, nullptr, 64, 1, flag);

        // LN1 + PReLU in place, both relations (2*Nc rows)
        ln1_k<<<2 * Nc, blk, 0, stream>>>(x1, g1, be1, a1, flag);

        // x2[r][:,ch,:] = x1[r][:,ch,:] @ W2T[ch]^T + b2[ch]: z=r*5+ch, zdiv=5
        mgemm<128, 64, 1, 1><<<dim3(4, Nc / 128, 10), blk, 0, stream>>>(
            x1, 1, 0, (long)Nc * 2560, 512, 2560,
            W2T, 0, 0, 262144,
            x2, 0, (long)Nc * 2560, 512, 2560,
            b2, 0, 0, 512, nullptr, 512, 5, flag);

        // LN2 + PReLU + channel pool -> hbc [Nc][2][512]
        ln2_pool_k<<<dim3(Nc, 2), blk, 0, stream>>>(
            x2, (long)Nc * 2560, g2, be2, a2, wr, hbc, flag);

        // global pool over R -> fin [Nc][512] (aliases x2, now dead)
        gpool_k<<<Nc, blk, 0, stream>>>(hbc, wg, fin, flag);

        // z = PReLU(fin @ Wf1T^T + bf1)
        mgemm<128, 64, 2, 1><<<dim3(4, Nc / 128, 1), blk, 0, stream>>>(
            fin, 1, 0, 0, 0, 512,
            Wf1T, 0, 0, 0,
            zb, 0, 0, 0, 512,
            bf1, 0, 0, 0, af, 512, 1, flag);
        // out = z @ Wf2T^T + bf2
        mgemm<64, 32, 1, 2><<<dim3(1, Nc / 128, 1), blk, 0, stream>>>(
            zb, 1, 0, 0, 0, 512,
            Wf2T, 0, 0, 0,
            d_out, n0 * 64, 0, 0, 64,
            bf2b, 0, 0, 0, nullptr, 512, 1, flag);
    }
}